// Round 1
// baseline (1131.787 us; speedup 1.0000x reference)
//
#include <hip/hip_runtime.h>

// GCN 2-layer, N=100000 nodes, E=1.6M edges, 64->64(relu)->32.
// out = D^-1/2 (A+I) D^-1/2 (X W) + b, twice.

constexpr int N = 100000;
constexpr int E = 1600000;

// ---- degree (in-edges per dst), +1 self-loop applied in rsqrt ----
__global__ void deg_kernel(const int* __restrict__ dst, float* __restrict__ deg) {
    int e = blockIdx.x * blockDim.x + threadIdx.x;
    if (e < E) atomicAdd(&deg[dst[e]], 1.0f);
}

__global__ void dis_kernel(const float* __restrict__ deg, float* __restrict__ dis) {
    int n = blockIdx.x * blockDim.x + threadIdx.x;
    if (n < N) dis[n] = rsqrtf(deg[n] + 1.0f);
}

// ---- H[N,M] = X[N,64] @ W[64,M], W staged in LDS, 16 rows/block ----
template<int M>
__global__ void gemm_kernel(const float* __restrict__ X, const float* __restrict__ W,
                            float* __restrict__ H) {
    __shared__ float ws[64][M];
    __shared__ float xs[16][65];  // +1 pad
    for (int i = threadIdx.x; i < 64 * M; i += 256) ws[i / M][i % M] = W[i];
    const int row0 = blockIdx.x * 16;
    for (int i = threadIdx.x; i < 16 * 64; i += 256) {
        int r = i >> 6, k = i & 63;
        int gr = row0 + r;
        xs[r][k] = (gr < N) ? X[gr * 64 + k] : 0.0f;
    }
    __syncthreads();
    constexpr int RPT = (16 * M) / 256;  // rows per thread: M=64 -> 4, M=32 -> 2
    const int c  = threadIdx.x % M;
    const int rb = (threadIdx.x / M) * RPT;
    float acc[RPT];
#pragma unroll
    for (int i = 0; i < RPT; ++i) acc[i] = 0.0f;
    for (int k = 0; k < 64; ++k) {
        float w = ws[k][c];
#pragma unroll
        for (int i = 0; i < RPT; ++i) acc[i] += xs[rb + i][k] * w;
    }
#pragma unroll
    for (int i = 0; i < RPT; ++i) {
        int gr = row0 + rb + i;
        if (gr < N) H[gr * M + c] = acc[i];
    }
}

// ---- edge scatter: agg[dst] += H[src] * dis[src]*dis[dst] ----
// thread-per-(edge,feature): F consecutive threads cover one edge's feature
// row -> coalesced gather + coalesced atomics.
template<int F>
__global__ void scatter_kernel(const float* __restrict__ H, const int* __restrict__ src,
                               const int* __restrict__ dst, const float* __restrict__ dis,
                               float* __restrict__ agg) {
    int tid = blockIdx.x * blockDim.x + threadIdx.x;
    int e = tid / F;
    int f = tid % F;
    if (e < E) {
        int s = src[e], d = dst[e];
        float norm = dis[s] * dis[d];
        atomicAdd(&agg[d * F + f], H[s * F + f] * norm);
    }
}

// ---- epilogues: add self-loop + bias (+ relu for layer 1) ----
__global__ void finalize1_kernel(float* __restrict__ agg, const float* __restrict__ H,
                                 const float* __restrict__ dis, const float* __restrict__ b) {
    int i = blockIdx.x * blockDim.x + threadIdx.x;
    if (i < N * 64) {
        int n = i >> 6, j = i & 63;
        float dd = dis[n] * dis[n];
        float v = agg[i] + H[i] * dd + b[j];
        agg[i] = v > 0.0f ? v : 0.0f;  // in place: agg becomes relu'd layer-1 out
    }
}

__global__ void finalize2_kernel(float* __restrict__ out, const float* __restrict__ H,
                                 const float* __restrict__ dis, const float* __restrict__ b) {
    int i = blockIdx.x * blockDim.x + threadIdx.x;
    if (i < N * 32) {
        int n = i >> 5, j = i & 31;
        float dd = dis[n] * dis[n];
        out[i] = out[i] + H[i] * dd + b[j];
    }
}

extern "C" void kernel_launch(void* const* d_in, const int* in_sizes, int n_in,
                              void* d_out, int out_size, void* d_ws, size_t ws_size,
                              hipStream_t stream) {
    const float* x  = (const float*)d_in[0];
    const int*   ei = (const int*)d_in[1];   // [2, E] int32
    const float* W1 = (const float*)d_in[2];
    const float* b1 = (const float*)d_in[3];
    const float* W2 = (const float*)d_in[4];
    const float* b2 = (const float*)d_in[5];
    float* out = (float*)d_out;

    const int* src = ei;
    const int* dst = ei + E;

    // workspace layout (floats), 64-elt aligned chunks
    float* w    = (float*)d_ws;
    float* deg  = w;                         // N
    float* dis  = deg + 100032;              // N
    float* h1   = dis + 100032;              // N*64
    float* agg1 = h1 + N * 64;               // N*64 (becomes relu'd layer-1 output)
    float* h2   = agg1 + N * 64;             // N*32
    // total: ~64.8 MB

    hipMemsetAsync(deg, 0, N * sizeof(float), stream);
    deg_kernel<<<(E + 255) / 256, 256, 0, stream>>>(dst, deg);
    dis_kernel<<<(N + 255) / 256, 256, 0, stream>>>(deg, dis);

    // layer 1
    gemm_kernel<64><<<(N + 15) / 16, 256, 0, stream>>>(x, W1, h1);
    hipMemsetAsync(agg1, 0, (size_t)N * 64 * sizeof(float), stream);
    scatter_kernel<64><<<(int)(((long long)E * 64 + 255) / 256), 256, 0, stream>>>(
        h1, src, dst, dis, agg1);
    finalize1_kernel<<<(N * 64 + 255) / 256, 256, 0, stream>>>(agg1, h1, dis, b1);

    // layer 2 (GEMM first so we only scatter 32 features)
    gemm_kernel<32><<<(N + 15) / 16, 256, 0, stream>>>(agg1, W2, h2);
    hipMemsetAsync(out, 0, (size_t)N * 32 * sizeof(float), stream);
    scatter_kernel<32><<<(int)(((long long)E * 32 + 255) / 256), 256, 0, stream>>>(
        h2, src, dst, dis, out);
    finalize2_kernel<<<(N * 32 + 255) / 256, 256, 0, stream>>>(out, h2, dis, b2);
}

// Round 2
// 945.102 us; speedup vs baseline: 1.1975x; 1.1975x over previous
//
#include <hip/hip_runtime.h>

// GCN 2-layer, N=100000 nodes, E=1.6M edges, 64->64(relu)->32.
// Strategy: counting-sort edges by dst once, then atomic-free wave-per-node
// aggregation with fused epilogues.

constexpr int N = 100000;
constexpr int E = 1600000;

// ---- histogram of in-degree (int) ----
__global__ void hist_kernel(const int* __restrict__ dst, int* __restrict__ cnt) {
    int e = blockIdx.x * blockDim.x + threadIdx.x;
    if (e < E) atomicAdd(&cnt[dst[e]], 1);
}

__global__ void dis_kernel(const int* __restrict__ cnt, float* __restrict__ dis) {
    int n = blockIdx.x * blockDim.x + threadIdx.x;
    if (n < N) dis[n] = rsqrtf((float)cnt[n] + 1.0f);
}

// ---- single-block exclusive scan of cnt[N] -> off[N+1] ----
__global__ void scan_kernel(const int* __restrict__ cnt, int* __restrict__ off) {
    __shared__ int sdata[1024];
    const int t = threadIdx.x;
    const int CPT = (N + 1023) / 1024;  // 98
    const int i0 = t * CPT;
    const int i1 = (i0 + CPT < N) ? i0 + CPT : N;
    int sum = 0;
    for (int i = i0; i < i1; ++i) sum += cnt[i];
    sdata[t] = sum;
    __syncthreads();
    for (int s = 1; s < 1024; s <<= 1) {
        int v = (t >= s) ? sdata[t - s] : 0;
        __syncthreads();
        sdata[t] += v;
        __syncthreads();
    }
    int run = sdata[t] - sum;  // exclusive prefix of this chunk
    for (int i = i0; i < i1; ++i) { off[i] = run; run += cnt[i]; }
    if (t == 1023) off[N] = sdata[1023];
}

// ---- place edges into dst-sorted order; precompute per-edge norm ----
__global__ void place_kernel(const int* __restrict__ src, const int* __restrict__ dst,
                             const float* __restrict__ dis, const int* __restrict__ off,
                             int* __restrict__ cursor,
                             int* __restrict__ psrc, float* __restrict__ pnorm) {
    int e = blockIdx.x * blockDim.x + threadIdx.x;
    if (e < E) {
        int s = src[e], d = dst[e];
        int p = atomicAdd(&cursor[d], 1);
        int i = off[d] + p;
        psrc[i]  = s;
        pnorm[i] = dis[s] * dis[d];
    }
}

// ---- H[N,M] = X[N,64] @ W[64,M], W + X tile staged in LDS ----
template<int M>
__global__ void gemm_kernel(const float* __restrict__ X, const float* __restrict__ W,
                            float* __restrict__ H) {
    __shared__ float ws[64][M];
    __shared__ float xs[16][65];
    for (int i = threadIdx.x; i < 64 * M; i += 256) ws[i / M][i % M] = W[i];
    const int row0 = blockIdx.x * 16;
    for (int i = threadIdx.x; i < 16 * 64; i += 256) {
        int r = i >> 6, k = i & 63;
        int gr = row0 + r;
        xs[r][k] = (gr < N) ? X[gr * 64 + k] : 0.0f;
    }
    __syncthreads();
    constexpr int RPT = (16 * M) / 256;
    const int c  = threadIdx.x % M;
    const int rb = (threadIdx.x / M) * RPT;
    float acc[RPT];
#pragma unroll
    for (int i = 0; i < RPT; ++i) acc[i] = 0.0f;
    for (int k = 0; k < 64; ++k) {
        float w = ws[k][c];
#pragma unroll
        for (int i = 0; i < RPT; ++i) acc[i] += xs[rb + i][k] * w;
    }
#pragma unroll
    for (int i = 0; i < RPT; ++i) {
        int gr = row0 + rb + i;
        if (gr < N) H[gr * M + c] = acc[i];
    }
}

// ---- layer-1 aggregation, fused self-loop + bias + relu. Wave per node.
// Lane layout: 4 edge-slots x 16 lanes x float4 (64 features). ----
__global__ void agg1_kernel(const float* __restrict__ h, const int* __restrict__ psrc,
                            const float* __restrict__ pnorm, const int* __restrict__ off,
                            const float* __restrict__ dis, const float* __restrict__ b,
                            float* __restrict__ out) {
    int n = (blockIdx.x * blockDim.x + threadIdx.x) >> 6;
    int lane = threadIdx.x & 63;
    if (n >= N) return;
    const int start = off[n], end = off[n + 1];
    const int q  = lane >> 4;        // edge slot 0..3
    const int fq = (lane & 15) * 4;  // feature base
    float4 acc = make_float4(0.f, 0.f, 0.f, 0.f);
    for (int j = start + q; j < end; j += 4) {
        int s = psrc[j];
        float w = pnorm[j];
        float4 v = *(const float4*)(h + (size_t)s * 64 + fq);
        acc.x += v.x * w; acc.y += v.y * w; acc.z += v.z * w; acc.w += v.w * w;
    }
    acc.x += __shfl_xor(acc.x, 16); acc.y += __shfl_xor(acc.y, 16);
    acc.z += __shfl_xor(acc.z, 16); acc.w += __shfl_xor(acc.w, 16);
    acc.x += __shfl_xor(acc.x, 32); acc.y += __shfl_xor(acc.y, 32);
    acc.z += __shfl_xor(acc.z, 32); acc.w += __shfl_xor(acc.w, 32);
    if (q == 0) {
        float dd = dis[n] * dis[n];
        float4 hv = *(const float4*)(h + (size_t)n * 64 + fq);
        float4 bv = *(const float4*)(b + fq);
        float4 r;
        r.x = fmaxf(acc.x + hv.x * dd + bv.x, 0.f);
        r.y = fmaxf(acc.y + hv.y * dd + bv.y, 0.f);
        r.z = fmaxf(acc.z + hv.z * dd + bv.z, 0.f);
        r.w = fmaxf(acc.w + hv.w * dd + bv.w, 0.f);
        *(float4*)(out + (size_t)n * 64 + fq) = r;
    }
}

// ---- layer-2 aggregation, fused self-loop + bias. Wave per node.
// Lane layout: 8 edge-slots x 8 lanes x float4 (32 features). ----
__global__ void agg2_kernel(const float* __restrict__ h, const int* __restrict__ psrc,
                            const float* __restrict__ pnorm, const int* __restrict__ off,
                            const float* __restrict__ dis, const float* __restrict__ b,
                            float* __restrict__ out) {
    int n = (blockIdx.x * blockDim.x + threadIdx.x) >> 6;
    int lane = threadIdx.x & 63;
    if (n >= N) return;
    const int start = off[n], end = off[n + 1];
    const int q  = lane >> 3;       // edge slot 0..7
    const int fq = (lane & 7) * 4;  // feature base
    float4 acc = make_float4(0.f, 0.f, 0.f, 0.f);
    for (int j = start + q; j < end; j += 8) {
        int s = psrc[j];
        float w = pnorm[j];
        float4 v = *(const float4*)(h + (size_t)s * 32 + fq);
        acc.x += v.x * w; acc.y += v.y * w; acc.z += v.z * w; acc.w += v.w * w;
    }
    acc.x += __shfl_xor(acc.x, 8);  acc.y += __shfl_xor(acc.y, 8);
    acc.z += __shfl_xor(acc.z, 8);  acc.w += __shfl_xor(acc.w, 8);
    acc.x += __shfl_xor(acc.x, 16); acc.y += __shfl_xor(acc.y, 16);
    acc.z += __shfl_xor(acc.z, 16); acc.w += __shfl_xor(acc.w, 16);
    acc.x += __shfl_xor(acc.x, 32); acc.y += __shfl_xor(acc.y, 32);
    acc.z += __shfl_xor(acc.z, 32); acc.w += __shfl_xor(acc.w, 32);
    if (q == 0) {
        float dd = dis[n] * dis[n];
        float4 hv = *(const float4*)(h + (size_t)n * 32 + fq);
        float4 bv = *(const float4*)(b + fq);
        float4 r;
        r.x = acc.x + hv.x * dd + bv.x;
        r.y = acc.y + hv.y * dd + bv.y;
        r.z = acc.z + hv.z * dd + bv.z;
        r.w = acc.w + hv.w * dd + bv.w;
        *(float4*)(out + (size_t)n * 32 + fq) = r;
    }
}

extern "C" void kernel_launch(void* const* d_in, const int* in_sizes, int n_in,
                              void* d_out, int out_size, void* d_ws, size_t ws_size,
                              hipStream_t stream) {
    const float* x  = (const float*)d_in[0];
    const int*   ei = (const int*)d_in[1];
    const float* W1 = (const float*)d_in[2];
    const float* b1 = (const float*)d_in[3];
    const float* W2 = (const float*)d_in[4];
    const float* b2 = (const float*)d_in[5];
    float* out = (float*)d_out;

    const int* src = ei;
    const int* dst = ei + E;

    // workspace layout (padded to 1024-float boundaries)
    constexpr size_t NP = 100352;  // N padded
    char* w = (char*)d_ws;
    int*   cnt    = (int*)w;                           // N
    int*   cursor = cnt + NP;                          // N
    int*   off    = cursor + NP;                       // N+1
    float* dis    = (float*)(off + NP);                // N
    int*   psrc   = (int*)(dis + NP);                  // E
    float* pnorm  = (float*)(psrc + E);                // E
    float* h1     = pnorm + E;                         // N*64
    float* z1     = h1 + (size_t)N * 64;               // N*64
    float* h2     = h1;                                // alias: h1 dead after agg1

    hipMemsetAsync(cnt, 0, NP * sizeof(int), stream);
    hipMemsetAsync(cursor, 0, NP * sizeof(int), stream);

    hist_kernel<<<(E + 255) / 256, 256, 0, stream>>>(dst, cnt);
    dis_kernel<<<(N + 255) / 256, 256, 0, stream>>>(cnt, dis);
    scan_kernel<<<1, 1024, 0, stream>>>(cnt, off);
    place_kernel<<<(E + 255) / 256, 256, 0, stream>>>(src, dst, dis, off, cursor,
                                                      psrc, pnorm);

    // layer 1
    gemm_kernel<64><<<(N + 15) / 16, 256, 0, stream>>>(x, W1, h1);
    agg1_kernel<<<(N * 64 + 255) / 256, 256, 0, stream>>>(h1, psrc, pnorm, off,
                                                          dis, b1, z1);
    // layer 2 (GEMM first: scatter only 32 features)
    gemm_kernel<32><<<(N + 15) / 16, 256, 0, stream>>>(z1, W2, h2);
    agg2_kernel<<<(N * 64 + 255) / 256, 256, 0, stream>>>(h2, psrc, pnorm, off,
                                                          dis, b2, out);
}

// Round 3
// 887.621 us; speedup vs baseline: 1.2751x; 1.0648x over previous
//
#include <hip/hip_runtime.h>
#include <hip/hip_bf16.h>

// GCN 2-layer, N=100000 nodes, E=1.6M edges, 64->64(relu)->32.
// Counting-sort edges by dst once; atomic-free wave-per-node aggregation.
// Gathered feature rows stored bf16 (halves random-gather traffic); f32 accum.

constexpr int N = 100000;
constexpr int E = 1600000;

__global__ void hist_kernel(const int* __restrict__ dst, int* __restrict__ cnt) {
    int e = blockIdx.x * blockDim.x + threadIdx.x;
    if (e < E) atomicAdd(&cnt[dst[e]], 1);
}

__global__ void dis_kernel(const int* __restrict__ cnt, float* __restrict__ dis) {
    int n = blockIdx.x * blockDim.x + threadIdx.x;
    if (n < N) dis[n] = rsqrtf((float)cnt[n] + 1.0f);
}

// single-block exclusive scan of cnt[N] -> off[N+1]
__global__ void scan_kernel(const int* __restrict__ cnt, int* __restrict__ off) {
    __shared__ int sdata[1024];
    const int t = threadIdx.x;
    const int CPT = (N + 1023) / 1024;
    const int i0 = t * CPT;
    const int i1 = (i0 + CPT < N) ? i0 + CPT : N;
    int sum = 0;
    for (int i = i0; i < i1; ++i) sum += cnt[i];
    sdata[t] = sum;
    __syncthreads();
    for (int s = 1; s < 1024; s <<= 1) {
        int v = (t >= s) ? sdata[t - s] : 0;
        __syncthreads();
        sdata[t] += v;
        __syncthreads();
    }
    int run = sdata[t] - sum;
    for (int i = i0; i < i1; ++i) { off[i] = run; run += cnt[i]; }
    if (t == 1023) off[N] = sdata[1023];
}

// place edges dst-sorted; pack (src, norm) into int2
__global__ void place_kernel(const int* __restrict__ src, const int* __restrict__ dst,
                             const float* __restrict__ dis, const int* __restrict__ off,
                             int* __restrict__ cursor, int2* __restrict__ pedge) {
    int e = blockIdx.x * blockDim.x + threadIdx.x;
    if (e < E) {
        int s = src[e], d = dst[e];
        int p = atomicAdd(&cursor[d], 1);
        float norm = dis[s] * dis[d];
        pedge[off[d] + p] = make_int2(s, __float_as_int(norm));
    }
}

// H[N,M] = X[N,64] @ W[64,M] -> bf16 output
template<int M>
__global__ void gemm_kernel(const float* __restrict__ X, const float* __restrict__ W,
                            __hip_bfloat16* __restrict__ Hb) {
    __shared__ float ws[64][M];
    __shared__ float xs[16][65];
    for (int i = threadIdx.x; i < 64 * M; i += 256) ws[i / M][i % M] = W[i];
    const int row0 = blockIdx.x * 16;
    for (int i = threadIdx.x; i < 16 * 64; i += 256) {
        int r = i >> 6, k = i & 63;
        int gr = row0 + r;
        xs[r][k] = (gr < N) ? X[gr * 64 + k] : 0.0f;
    }
    __syncthreads();
    constexpr int RPT = (16 * M) / 256;
    const int c  = threadIdx.x % M;
    const int rb = (threadIdx.x / M) * RPT;
    float acc[RPT];
#pragma unroll
    for (int i = 0; i < RPT; ++i) acc[i] = 0.0f;
    for (int k = 0; k < 64; ++k) {
        float w = ws[k][c];
#pragma unroll
        for (int i = 0; i < RPT; ++i) acc[i] += xs[rb + i][k] * w;
    }
#pragma unroll
    for (int i = 0; i < RPT; ++i) {
        int gr = row0 + rb + i;
        if (gr < N) Hb[(size_t)gr * M + c] = __float2bfloat16(acc[i]);
    }
}

__device__ __forceinline__ void bf8_fma(float* acc, uint4 r, float w) {
    const unsigned u[4] = {r.x, r.y, r.z, r.w};
#pragma unroll
    for (int k = 0; k < 4; ++k) {
        float lo = __uint_as_float(u[k] << 16);
        float hi = __uint_as_float(u[k] & 0xffff0000u);
        acc[2 * k]     += lo * w;
        acc[2 * k + 1] += hi * w;
    }
}

// layer-1 agg: wave/node, 8 edge-slots x 8 lanes x 8 bf16 feats, unroll x2.
// fused self-loop + bias + relu; z1 f32 out.
__global__ void agg1_kernel(const __hip_bfloat16* __restrict__ h,
                            const int2* __restrict__ pedge, const int* __restrict__ off,
                            const float* __restrict__ dis, const float* __restrict__ b,
                            float* __restrict__ z) {
    int n = (blockIdx.x * blockDim.x + threadIdx.x) >> 6;
    int lane = threadIdx.x & 63;
    if (n >= N) return;
    const int start = off[n], end = off[n + 1];
    const int q  = lane >> 3;       // slot 0..7
    const int fq = (lane & 7) * 8;  // feature base (8 feats)
    const unsigned short* hp = (const unsigned short*)h;
    float acc[8];
#pragma unroll
    for (int i = 0; i < 8; ++i) acc[i] = 0.0f;
    for (int j = start + q; j < end; j += 16) {
        int2 e0 = pedge[j];
        uint4 r0 = *(const uint4*)(hp + (size_t)e0.x * 64 + fq);
        int j2 = j + 8;
        if (j2 < end) {
            int2 e1 = pedge[j2];
            uint4 r1 = *(const uint4*)(hp + (size_t)e1.x * 64 + fq);
            bf8_fma(acc, r0, __int_as_float(e0.y));
            bf8_fma(acc, r1, __int_as_float(e1.y));
        } else {
            bf8_fma(acc, r0, __int_as_float(e0.y));
        }
    }
#pragma unroll
    for (int i = 0; i < 8; ++i) {
        acc[i] += __shfl_xor(acc[i], 8);
        acc[i] += __shfl_xor(acc[i], 16);
        acc[i] += __shfl_xor(acc[i], 32);
    }
    if (q == 0) {
        float dd = dis[n] * dis[n];
        uint4 sr = *(const uint4*)(hp + (size_t)n * 64 + fq);
        float sl[8];
#pragma unroll
        for (int i = 0; i < 8; ++i) sl[i] = 0.0f;
        bf8_fma(sl, sr, dd);
        float4 b0 = *(const float4*)(b + fq);
        float4 b1 = *(const float4*)(b + fq + 4);
        float o[8];
        o[0] = fmaxf(acc[0] + sl[0] + b0.x, 0.f);
        o[1] = fmaxf(acc[1] + sl[1] + b0.y, 0.f);
        o[2] = fmaxf(acc[2] + sl[2] + b0.z, 0.f);
        o[3] = fmaxf(acc[3] + sl[3] + b0.w, 0.f);
        o[4] = fmaxf(acc[4] + sl[4] + b1.x, 0.f);
        o[5] = fmaxf(acc[5] + sl[5] + b1.y, 0.f);
        o[6] = fmaxf(acc[6] + sl[6] + b1.z, 0.f);
        o[7] = fmaxf(acc[7] + sl[7] + b1.w, 0.f);
        *(float4*)(z + (size_t)n * 64 + fq)     = make_float4(o[0], o[1], o[2], o[3]);
        *(float4*)(z + (size_t)n * 64 + fq + 4) = make_float4(o[4], o[5], o[6], o[7]);
    }
}

// layer-2 agg: wave/node, 16 edge-slots x 4 lanes x 8 bf16 feats.
// fused self-loop + bias; f32 out.
__global__ void agg2_kernel(const __hip_bfloat16* __restrict__ h,
                            const int2* __restrict__ pedge, const int* __restrict__ off,
                            const float* __restrict__ dis, const float* __restrict__ b,
                            float* __restrict__ out) {
    int n = (blockIdx.x * blockDim.x + threadIdx.x) >> 6;
    int lane = threadIdx.x & 63;
    if (n >= N) return;
    const int start = off[n], end = off[n + 1];
    const int q  = lane >> 2;       // slot 0..15
    const int fq = (lane & 3) * 8;  // feature base
    const unsigned short* hp = (const unsigned short*)h;
    float acc[8];
#pragma unroll
    for (int i = 0; i < 8; ++i) acc[i] = 0.0f;
    for (int j = start + q; j < end; j += 16) {
        int2 e0 = pedge[j];
        uint4 r0 = *(const uint4*)(hp + (size_t)e0.x * 32 + fq);
        bf8_fma(acc, r0, __int_as_float(e0.y));
    }
#pragma unroll
    for (int i = 0; i < 8; ++i) {
        acc[i] += __shfl_xor(acc[i], 4);
        acc[i] += __shfl_xor(acc[i], 8);
        acc[i] += __shfl_xor(acc[i], 16);
        acc[i] += __shfl_xor(acc[i], 32);
    }
    if (q == 0) {
        float dd = dis[n] * dis[n];
        uint4 sr = *(const uint4*)(hp + (size_t)n * 32 + fq);
        float sl[8];
#pragma unroll
        for (int i = 0; i < 8; ++i) sl[i] = 0.0f;
        bf8_fma(sl, sr, dd);
        float4 b0 = *(const float4*)(b + fq);
        float4 b1 = *(const float4*)(b + fq + 4);
        float o[8];
        o[0] = acc[0] + sl[0] + b0.x;
        o[1] = acc[1] + sl[1] + b0.y;
        o[2] = acc[2] + sl[2] + b0.z;
        o[3] = acc[3] + sl[3] + b0.w;
        o[4] = acc[4] + sl[4] + b1.x;
        o[5] = acc[5] + sl[5] + b1.y;
        o[6] = acc[6] + sl[6] + b1.z;
        o[7] = acc[7] + sl[7] + b1.w;
        *(float4*)(out + (size_t)n * 32 + fq)     = make_float4(o[0], o[1], o[2], o[3]);
        *(float4*)(out + (size_t)n * 32 + fq + 4) = make_float4(o[4], o[5], o[6], o[7]);
    }
}

extern "C" void kernel_launch(void* const* d_in, const int* in_sizes, int n_in,
                              void* d_out, int out_size, void* d_ws, size_t ws_size,
                              hipStream_t stream) {
    const float* x  = (const float*)d_in[0];
    const int*   ei = (const int*)d_in[1];
    const float* W1 = (const float*)d_in[2];
    const float* b1 = (const float*)d_in[3];
    const float* W2 = (const float*)d_in[4];
    const float* b2 = (const float*)d_in[5];
    float* out = (float*)d_out;

    const int* src = ei;
    const int* dst = ei + E;

    constexpr size_t NP = 100352;
    int*   cnt    = (int*)d_ws;                        // NP
    int*   cursor = cnt + NP;                          // NP
    int*   off    = cursor + NP;                       // NP (N+1 used)
    float* dis    = (float*)(off + NP);                // NP
    int2*  pedge  = (int2*)(dis + NP);                 // E
    __hip_bfloat16* h1b = (__hip_bfloat16*)(pedge + E);        // N*64
    float* z1     = (float*)(h1b + (size_t)N * 64);            // N*64
    __hip_bfloat16* h2b = (__hip_bfloat16*)(z1 + (size_t)N * 64); // N*32

    hipMemsetAsync(cnt, 0, NP * sizeof(int), stream);
    hipMemsetAsync(cursor, 0, NP * sizeof(int), stream);

    hist_kernel<<<(E + 255) / 256, 256, 0, stream>>>(dst, cnt);
    dis_kernel<<<(N + 255) / 256, 256, 0, stream>>>(cnt, dis);
    scan_kernel<<<1, 1024, 0, stream>>>(cnt, off);
    place_kernel<<<(E + 255) / 256, 256, 0, stream>>>(src, dst, dis, off, cursor, pedge);

    gemm_kernel<64><<<(N + 15) / 16, 256, 0, stream>>>(x, W1, h1b);
    agg1_kernel<<<(N * 64 + 255) / 256, 256, 0, stream>>>(h1b, pedge, off, dis, b1, z1);

    gemm_kernel<32><<<(N + 15) / 16, 256, 0, stream>>>(z1, W2, h2b);
    agg2_kernel<<<(N * 64 + 255) / 256, 256, 0, stream>>>(h2b, pedge, off, dis, b2, out);
}

// Round 4
// 534.374 us; speedup vs baseline: 2.1180x; 1.6611x over previous
//
#include <hip/hip_runtime.h>
#include <hip/hip_bf16.h>

// GCN 2-layer, N=100000 nodes, E=1.6M edges, 64->64(relu)->32.
// Counting-sort edges by dst (rank fused into histogram), 4B packed edge
// records (src:17b | norm:q15), atomic-free wave-per-node aggregation with
// bf16 feature rows and fused epilogues.

constexpr int N = 100000;
constexpr int E = 1600000;

// ---- pass 1: in-degree histogram + per-edge rank within its dst bucket ----
__global__ void rank_kernel(const int* __restrict__ dst, int* __restrict__ cnt,
                            int* __restrict__ rank) {
    int e = blockIdx.x * blockDim.x + threadIdx.x;
    if (e < E) rank[e] = atomicAdd(&cnt[dst[e]], 1);
}

// ---- single-block: exclusive scan cnt->off, plus dis = rsqrt(deg+1) ----
__global__ void scan_dis_kernel(const int* __restrict__ cnt, int* __restrict__ off,
                                float* __restrict__ dis) {
    __shared__ int sdata[1024];
    const int t = threadIdx.x;
    const int CPT = (N + 1023) / 1024;  // 98
    const int i0 = t * CPT;
    const int i1 = (i0 + CPT < N) ? i0 + CPT : N;
    int sum = 0;
    for (int i = i0; i < i1; ++i) sum += cnt[i];
    sdata[t] = sum;
    __syncthreads();
    for (int s = 1; s < 1024; s <<= 1) {
        int v = (t >= s) ? sdata[t - s] : 0;
        __syncthreads();
        sdata[t] += v;
        __syncthreads();
    }
    int run = sdata[t] - sum;
    for (int i = i0; i < i1; ++i) {
        int c = cnt[i];
        off[i] = run;
        dis[i] = rsqrtf((float)c + 1.0f);
        run += c;
    }
    if (t == 1023) off[N] = sdata[1023];
}

// ---- pass 2: place packed edge records, no atomics ----
// pedge[i] = (src << 15) | q15(dis[src]*dis[dst]);  norm <= 0.7071 < 1.
__global__ void place_kernel(const int* __restrict__ src, const int* __restrict__ dst,
                             const int* __restrict__ rank, const float* __restrict__ dis,
                             const int* __restrict__ off, unsigned* __restrict__ pedge) {
    int e = blockIdx.x * blockDim.x + threadIdx.x;
    if (e < E) {
        int s = src[e], d = dst[e];
        float norm = dis[s] * dis[d];
        unsigned q = (unsigned)(norm * 32767.0f + 0.5f);
        pedge[off[d] + rank[e]] = ((unsigned)s << 15) | q;
    }
}

// ---- H[N,M] = X[N,64] @ W[64,M] -> bf16. 32 rows/block (3125 blocks exact).
template<int M, bool IN_BF16>
__global__ void gemm_kernel(const void* __restrict__ Xv, const float* __restrict__ W,
                            __hip_bfloat16* __restrict__ Hb) {
    __shared__ float ws[64][M];
    __shared__ float xs[32][65];
    for (int i = threadIdx.x; i < 64 * M; i += 256) ws[i / M][i % M] = W[i];
    const int row0 = blockIdx.x * 32;
    // stage 32x64 input tile: 2048 elems, 4 per thread per half
#pragma unroll
    for (int h = 0; h < 2; ++h) {
        int idx = h * 1024 + threadIdx.x * 4;
        int r = idx >> 6, k = idx & 63;
        if constexpr (IN_BF16) {
            const unsigned short* X = (const unsigned short*)Xv;
            ushort4 v = *(const ushort4*)(X + (size_t)(row0 + r) * 64 + k);
            xs[r][k]     = __uint_as_float((unsigned)v.x << 16);
            xs[r][k + 1] = __uint_as_float((unsigned)v.y << 16);
            xs[r][k + 2] = __uint_as_float((unsigned)v.z << 16);
            xs[r][k + 3] = __uint_as_float((unsigned)v.w << 16);
        } else {
            const float* X = (const float*)Xv;
            float4 v = *(const float4*)(X + (size_t)(row0 + r) * 64 + k);
            xs[r][k] = v.x; xs[r][k + 1] = v.y; xs[r][k + 2] = v.z; xs[r][k + 3] = v.w;
        }
    }
    __syncthreads();
    constexpr int RPT = (32 * M) / 256;  // M=64 -> 8, M=32 -> 4
    const int c  = threadIdx.x % M;
    const int rb = (threadIdx.x / M) * RPT;
    float acc[RPT];
#pragma unroll
    for (int i = 0; i < RPT; ++i) acc[i] = 0.0f;
    for (int k = 0; k < 64; ++k) {
        float w = ws[k][c];
#pragma unroll
        for (int i = 0; i < RPT; ++i) acc[i] += xs[rb + i][k] * w;
    }
#pragma unroll
    for (int i = 0; i < RPT; ++i)
        Hb[(size_t)(row0 + rb + i) * M + c] = __float2bfloat16(acc[i]);
}

__device__ __forceinline__ void bf8_fma(float* acc, uint4 r, float w) {
    const unsigned u[4] = {r.x, r.y, r.z, r.w};
#pragma unroll
    for (int k = 0; k < 4; ++k) {
        float lo = __uint_as_float(u[k] << 16);
        float hi = __uint_as_float(u[k] & 0xffff0000u);
        acc[2 * k]     += lo * w;
        acc[2 * k + 1] += hi * w;
    }
}

__device__ __forceinline__ void decode(unsigned p, int& s, float& w) {
    s = (int)(p >> 15);
    w = (float)(p & 0x7fffu) * (1.0f / 32767.0f);
}

// ---- layer-1 agg: wave/node, 8 slots x 8 lanes x 8 bf16 feats, unroll x2.
// fused self-loop + bias + relu; z out bf16. ----
__global__ void agg1_kernel(const __hip_bfloat16* __restrict__ h,
                            const unsigned* __restrict__ pedge, const int* __restrict__ off,
                            const float* __restrict__ dis, const float* __restrict__ b,
                            __hip_bfloat16* __restrict__ z) {
    int n = (blockIdx.x * blockDim.x + threadIdx.x) >> 6;
    int lane = threadIdx.x & 63;
    if (n >= N) return;
    const int start = off[n], end = off[n + 1];
    const int q  = lane >> 3;
    const int fq = (lane & 7) * 8;
    const unsigned short* hp = (const unsigned short*)h;
    float acc[8];
#pragma unroll
    for (int i = 0; i < 8; ++i) acc[i] = 0.0f;
    for (int j = start + q; j < end; j += 16) {
        int s0; float w0;
        decode(pedge[j], s0, w0);
        uint4 r0 = *(const uint4*)(hp + (size_t)s0 * 64 + fq);
        int j2 = j + 8;
        if (j2 < end) {
            int s1; float w1;
            decode(pedge[j2], s1, w1);
            uint4 r1 = *(const uint4*)(hp + (size_t)s1 * 64 + fq);
            bf8_fma(acc, r0, w0);
            bf8_fma(acc, r1, w1);
        } else {
            bf8_fma(acc, r0, w0);
        }
    }
#pragma unroll
    for (int i = 0; i < 8; ++i) {
        acc[i] += __shfl_xor(acc[i], 8);
        acc[i] += __shfl_xor(acc[i], 16);
        acc[i] += __shfl_xor(acc[i], 32);
    }
    if (q == 0) {
        float dd = dis[n] * dis[n];
        uint4 sr = *(const uint4*)(hp + (size_t)n * 64 + fq);
        float sl[8];
#pragma unroll
        for (int i = 0; i < 8; ++i) sl[i] = 0.0f;
        bf8_fma(sl, sr, dd);
        float4 b0 = *(const float4*)(b + fq);
        float4 b1 = *(const float4*)(b + fq + 4);
        float bb[8] = {b0.x, b0.y, b0.z, b0.w, b1.x, b1.y, b1.z, b1.w};
        unsigned short o[8];
#pragma unroll
        for (int i = 0; i < 8; ++i) {
            float v = fmaxf(acc[i] + sl[i] + bb[i], 0.0f);
            o[i] = (unsigned short)(__bfloat16_as_ushort(__float2bfloat16(v)));
        }
        *(uint4*)((unsigned short*)z + (size_t)n * 64 + fq) = *(const uint4*)o;
    }
}

// ---- layer-2 agg: wave/node, 16 slots x 4 lanes x 8 bf16 feats.
// fused self-loop + bias; f32 out. ----
__global__ void agg2_kernel(const __hip_bfloat16* __restrict__ h,
                            const unsigned* __restrict__ pedge, const int* __restrict__ off,
                            const float* __restrict__ dis, const float* __restrict__ b,
                            float* __restrict__ out) {
    int n = (blockIdx.x * blockDim.x + threadIdx.x) >> 6;
    int lane = threadIdx.x & 63;
    if (n >= N) return;
    const int start = off[n], end = off[n + 1];
    const int q  = lane >> 2;
    const int fq = (lane & 3) * 8;
    const unsigned short* hp = (const unsigned short*)h;
    float acc[8];
#pragma unroll
    for (int i = 0; i < 8; ++i) acc[i] = 0.0f;
    for (int j = start + q; j < end; j += 16) {
        int s0; float w0;
        decode(pedge[j], s0, w0);
        uint4 r0 = *(const uint4*)(hp + (size_t)s0 * 32 + fq);
        bf8_fma(acc, r0, w0);
    }
#pragma unroll
    for (int i = 0; i < 8; ++i) {
        acc[i] += __shfl_xor(acc[i], 4);
        acc[i] += __shfl_xor(acc[i], 8);
        acc[i] += __shfl_xor(acc[i], 16);
        acc[i] += __shfl_xor(acc[i], 32);
    }
    if (q == 0) {
        float dd = dis[n] * dis[n];
        uint4 sr = *(const uint4*)(hp + (size_t)n * 32 + fq);
        float sl[8];
#pragma unroll
        for (int i = 0; i < 8; ++i) sl[i] = 0.0f;
        bf8_fma(sl, sr, dd);
        float4 b0 = *(const float4*)(b + fq);
        float4 b1 = *(const float4*)(b + fq + 4);
        float bb[8] = {b0.x, b0.y, b0.z, b0.w, b1.x, b1.y, b1.z, b1.w};
        float o[8];
#pragma unroll
        for (int i = 0; i < 8; ++i) o[i] = acc[i] + sl[i] + bb[i];
        *(float4*)(out + (size_t)n * 32 + fq)     = make_float4(o[0], o[1], o[2], o[3]);
        *(float4*)(out + (size_t)n * 32 + fq + 4) = make_float4(o[4], o[5], o[6], o[7]);
    }
}

extern "C" void kernel_launch(void* const* d_in, const int* in_sizes, int n_in,
                              void* d_out, int out_size, void* d_ws, size_t ws_size,
                              hipStream_t stream) {
    const float* x  = (const float*)d_in[0];
    const int*   ei = (const int*)d_in[1];
    const float* W1 = (const float*)d_in[2];
    const float* b1 = (const float*)d_in[3];
    const float* W2 = (const float*)d_in[4];
    const float* b2 = (const float*)d_in[5];
    float* out = (float*)d_out;

    const int* src = ei;
    const int* dst = ei + E;

    constexpr size_t NP = 100352;
    int*      cnt   = (int*)d_ws;                         // NP
    int*      rank  = cnt + NP;                           // E
    int*      off   = rank + E;                           // NP (N+1 used)
    float*    dis   = (float*)(off + NP);                 // NP
    unsigned* pedge = (unsigned*)(dis + NP);              // E
    __hip_bfloat16* h1b = (__hip_bfloat16*)(pedge + E);             // N*64
    __hip_bfloat16* z1b = h1b + (size_t)N * 64;                     // N*64
    __hip_bfloat16* h2b = z1b + (size_t)N * 64;                     // N*32

    hipMemsetAsync(cnt, 0, NP * sizeof(int), stream);
    rank_kernel<<<(E + 255) / 256, 256, 0, stream>>>(dst, cnt, rank);
    scan_dis_kernel<<<1, 1024, 0, stream>>>(cnt, off, dis);
    place_kernel<<<(E + 255) / 256, 256, 0, stream>>>(src, dst, rank, dis, off, pedge);

    gemm_kernel<64, false><<<N / 32, 256, 0, stream>>>(x, W1, h1b);
    agg1_kernel<<<(N * 64 + 255) / 256, 256, 0, stream>>>(h1b, pedge, off, dis, b1, z1b);

    gemm_kernel<32, true><<<N / 32, 256, 0, stream>>>(z1b, W2, h2b);
    agg2_kernel<<<(N * 64 + 255) / 256, 256, 0, stream>>>(h2b, pedge, off, dis, b2, out);
}

// Round 5
// 317.987 us; speedup vs baseline: 3.5592x; 1.6805x over previous
//
#include <hip/hip_runtime.h>
#include <hip/hip_bf16.h>

// GCN 2-layer, N=100000 nodes, E=1.6M edges, 64->64(relu)->32.
// Counting-sort edges by dst (rank fused into histogram), 4B packed edge
// records (src:17b | norm:q15), atomic-free wave-per-node aggregation with
// bf16 feature rows and fused epilogues. Multi-block two-level scan.

constexpr int N = 100000;
constexpr int E = 1600000;
constexpr int NPI = 100352;            // N padded to 1024*98
constexpr int SCAN_BLOCKS = NPI / 1024;  // 98

// ---- pass 1: in-degree histogram + per-edge rank within its dst bucket ----
__global__ void rank_kernel(const int* __restrict__ dst, int* __restrict__ cnt,
                            int* __restrict__ rank) {
    int e = blockIdx.x * blockDim.x + threadIdx.x;
    if (e < E) rank[e] = atomicAdd(&cnt[dst[e]], 1);
}

// ---- scan level 1: per-block (1024 counts) sums ----
__global__ void blocksum_kernel(const int* __restrict__ cnt, int* __restrict__ bsum) {
    int t = threadIdx.x;
    int4 v = *(const int4*)(cnt + blockIdx.x * 1024 + t * 4);
    int s = v.x + v.y + v.z + v.w;
#pragma unroll
    for (int d = 1; d < 64; d <<= 1) s += __shfl_xor(s, d);
    __shared__ int ws[4];
    if ((t & 63) == 0) ws[t >> 6] = s;
    __syncthreads();
    if (t == 0) bsum[blockIdx.x] = ws[0] + ws[1] + ws[2] + ws[3];
}

// ---- scan level 2: tiny single-block exclusive scan of 98 block sums ----
__global__ void scan_bsum_kernel(const int* __restrict__ bsum, int* __restrict__ boff) {
    __shared__ int s[128];
    int t = threadIdx.x;
    int v = (t < SCAN_BLOCKS) ? bsum[t] : 0;
    s[t] = v;
    __syncthreads();
    for (int d = 1; d < 128; d <<= 1) {
        int u = (t >= d) ? s[t - d] : 0;
        __syncthreads();
        s[t] += u;
        __syncthreads();
    }
    if (t < SCAN_BLOCKS) boff[t] = s[t] - v;
}

// ---- scan level 3: per-block exclusive scan, write off[] + dis[] fused ----
__global__ void scan_write_kernel(const int* __restrict__ cnt, const int* __restrict__ boff,
                                  int* __restrict__ off, float* __restrict__ dis) {
    int t = threadIdx.x;
    int base_i = blockIdx.x * 1024 + t * 4;
    int4 v = *(const int4*)(cnt + base_i);
    int s = v.x + v.y + v.z + v.w;
    int lane = t & 63, w = t >> 6;
    int inc = s;
#pragma unroll
    for (int d = 1; d < 64; d <<= 1) {
        int u = __shfl_up(inc, d);
        if (lane >= d) inc += u;
    }
    __shared__ int wsum[4];
    if (lane == 63) wsum[w] = inc;
    __syncthreads();
    int excl = boff[blockIdx.x] + inc - s;
    for (int i = 0; i < w; ++i) excl += wsum[i];
    off[base_i] = excl;           dis[base_i]     = rsqrtf((float)v.x + 1.0f);
    excl += v.x;
    off[base_i + 1] = excl;       dis[base_i + 1] = rsqrtf((float)v.y + 1.0f);
    excl += v.y;
    off[base_i + 2] = excl;       dis[base_i + 2] = rsqrtf((float)v.z + 1.0f);
    excl += v.z;
    off[base_i + 3] = excl;       dis[base_i + 3] = rsqrtf((float)v.w + 1.0f);
}

// ---- pass 2: place packed edge records, no atomics ----
__global__ void place_kernel(const int* __restrict__ src, const int* __restrict__ dst,
                             const int* __restrict__ rank, const float* __restrict__ dis,
                             const int* __restrict__ off, unsigned* __restrict__ pedge) {
    int e = blockIdx.x * blockDim.x + threadIdx.x;
    if (e < E) {
        int s = src[e], d = dst[e];
        float norm = dis[s] * dis[d];
        unsigned q = (unsigned)(norm * 32767.0f + 0.5f);
        pedge[off[d] + rank[e]] = ((unsigned)s << 15) | q;
    }
}

// ---- H[N,M] = X[N,64] @ W[64,M] -> bf16. 32 rows/block (3125 blocks). ----
template<int M, bool IN_BF16>
__global__ void gemm_kernel(const void* __restrict__ Xv, const float* __restrict__ W,
                            __hip_bfloat16* __restrict__ Hb) {
    __shared__ float ws[64][M];
    __shared__ float xs[32][65];
    for (int i = threadIdx.x; i < 64 * M; i += 256) ws[i / M][i % M] = W[i];
    const int row0 = blockIdx.x * 32;
#pragma unroll
    for (int h = 0; h < 2; ++h) {
        int idx = h * 1024 + threadIdx.x * 4;
        int r = idx >> 6, k = idx & 63;
        if constexpr (IN_BF16) {
            const unsigned short* X = (const unsigned short*)Xv;
            ushort4 v = *(const ushort4*)(X + (size_t)(row0 + r) * 64 + k);
            xs[r][k]     = __uint_as_float((unsigned)v.x << 16);
            xs[r][k + 1] = __uint_as_float((unsigned)v.y << 16);
            xs[r][k + 2] = __uint_as_float((unsigned)v.z << 16);
            xs[r][k + 3] = __uint_as_float((unsigned)v.w << 16);
        } else {
            const float* X = (const float*)Xv;
            float4 v = *(const float4*)(X + (size_t)(row0 + r) * 64 + k);
            xs[r][k] = v.x; xs[r][k + 1] = v.y; xs[r][k + 2] = v.z; xs[r][k + 3] = v.w;
        }
    }
    __syncthreads();
    constexpr int RPT = (32 * M) / 256;
    const int c  = threadIdx.x % M;
    const int rb = (threadIdx.x / M) * RPT;
    float acc[RPT];
#pragma unroll
    for (int i = 0; i < RPT; ++i) acc[i] = 0.0f;
    for (int k = 0; k < 64; ++k) {
        float w = ws[k][c];
#pragma unroll
        for (int i = 0; i < RPT; ++i) acc[i] += xs[rb + i][k] * w;
    }
#pragma unroll
    for (int i = 0; i < RPT; ++i)
        Hb[(size_t)(row0 + rb + i) * M + c] = __float2bfloat16(acc[i]);
}

__device__ __forceinline__ void bf8_fma(float* acc, uint4 r, float w) {
    const unsigned u[4] = {r.x, r.y, r.z, r.w};
#pragma unroll
    for (int k = 0; k < 4; ++k) {
        float lo = __uint_as_float(u[k] << 16);
        float hi = __uint_as_float(u[k] & 0xffff0000u);
        acc[2 * k]     += lo * w;
        acc[2 * k + 1] += hi * w;
    }
}

__device__ __forceinline__ void decode(unsigned p, int& s, float& w) {
    s = (int)(p >> 15);
    w = (float)(p & 0x7fffu) * (1.0f / 32767.0f);
}

// ---- layer-1 agg: wave/node, 8 slots x 8 lanes x 8 bf16 feats, unroll x2.
// fused self-loop + bias + relu; z out bf16. ----
__global__ void agg1_kernel(const __hip_bfloat16* __restrict__ h,
                            const unsigned* __restrict__ pedge, const int* __restrict__ off,
                            const float* __restrict__ dis, const float* __restrict__ b,
                            __hip_bfloat16* __restrict__ z) {
    int n = (blockIdx.x * blockDim.x + threadIdx.x) >> 6;
    int lane = threadIdx.x & 63;
    if (n >= N) return;
    const int start = off[n], end = off[n + 1];
    const int q  = lane >> 3;
    const int fq = (lane & 7) * 8;
    const unsigned short* hp = (const unsigned short*)h;
    float acc[8];
#pragma unroll
    for (int i = 0; i < 8; ++i) acc[i] = 0.0f;
    for (int j = start + q; j < end; j += 16) {
        int s0; float w0;
        decode(pedge[j], s0, w0);
        uint4 r0 = *(const uint4*)(hp + (size_t)s0 * 64 + fq);
        int j2 = j + 8;
        if (j2 < end) {
            int s1; float w1;
            decode(pedge[j2], s1, w1);
            uint4 r1 = *(const uint4*)(hp + (size_t)s1 * 64 + fq);
            bf8_fma(acc, r0, w0);
            bf8_fma(acc, r1, w1);
        } else {
            bf8_fma(acc, r0, w0);
        }
    }
#pragma unroll
    for (int i = 0; i < 8; ++i) {
        acc[i] += __shfl_xor(acc[i], 8);
        acc[i] += __shfl_xor(acc[i], 16);
        acc[i] += __shfl_xor(acc[i], 32);
    }
    if (q == 0) {
        float dd = dis[n] * dis[n];
        uint4 sr = *(const uint4*)(hp + (size_t)n * 64 + fq);
        float sl[8];
#pragma unroll
        for (int i = 0; i < 8; ++i) sl[i] = 0.0f;
        bf8_fma(sl, sr, dd);
        float4 b0 = *(const float4*)(b + fq);
        float4 b1 = *(const float4*)(b + fq + 4);
        float bb[8] = {b0.x, b0.y, b0.z, b0.w, b1.x, b1.y, b1.z, b1.w};
        unsigned short o[8];
#pragma unroll
        for (int i = 0; i < 8; ++i) {
            float v = fmaxf(acc[i] + sl[i] + bb[i], 0.0f);
            o[i] = (unsigned short)(__bfloat16_as_ushort(__float2bfloat16(v)));
        }
        *(uint4*)((unsigned short*)z + (size_t)n * 64 + fq) = *(const uint4*)o;
    }
}

// ---- layer-2 agg: wave/node, 16 slots x 4 lanes x 8 bf16 feats.
// fused self-loop + bias; f32 out. ----
__global__ void agg2_kernel(const __hip_bfloat16* __restrict__ h,
                            const unsigned* __restrict__ pedge, const int* __restrict__ off,
                            const float* __restrict__ dis, const float* __restrict__ b,
                            float* __restrict__ out) {
    int n = (blockIdx.x * blockDim.x + threadIdx.x) >> 6;
    int lane = threadIdx.x & 63;
    if (n >= N) return;
    const int start = off[n], end = off[n + 1];
    const int q  = lane >> 2;
    const int fq = (lane & 3) * 8;
    const unsigned short* hp = (const unsigned short*)h;
    float acc[8];
#pragma unroll
    for (int i = 0; i < 8; ++i) acc[i] = 0.0f;
    for (int j = start + q; j < end; j += 16) {
        int s0; float w0;
        decode(pedge[j], s0, w0);
        uint4 r0 = *(const uint4*)(hp + (size_t)s0 * 32 + fq);
        bf8_fma(acc, r0, w0);
    }
#pragma unroll
    for (int i = 0; i < 8; ++i) {
        acc[i] += __shfl_xor(acc[i], 4);
        acc[i] += __shfl_xor(acc[i], 8);
        acc[i] += __shfl_xor(acc[i], 16);
        acc[i] += __shfl_xor(acc[i], 32);
    }
    if (q == 0) {
        float dd = dis[n] * dis[n];
        uint4 sr = *(const uint4*)(hp + (size_t)n * 32 + fq);
        float sl[8];
#pragma unroll
        for (int i = 0; i < 8; ++i) sl[i] = 0.0f;
        bf8_fma(sl, sr, dd);
        float4 b0 = *(const float4*)(b + fq);
        float4 b1 = *(const float4*)(b + fq + 4);
        float bb[8] = {b0.x, b0.y, b0.z, b0.w, b1.x, b1.y, b1.z, b1.w};
        float o[8];
#pragma unroll
        for (int i = 0; i < 8; ++i) o[i] = acc[i] + sl[i] + bb[i];
        *(float4*)(out + (size_t)n * 32 + fq)     = make_float4(o[0], o[1], o[2], o[3]);
        *(float4*)(out + (size_t)n * 32 + fq + 4) = make_float4(o[4], o[5], o[6], o[7]);
    }
}

extern "C" void kernel_launch(void* const* d_in, const int* in_sizes, int n_in,
                              void* d_out, int out_size, void* d_ws, size_t ws_size,
                              hipStream_t stream) {
    const float* x  = (const float*)d_in[0];
    const int*   ei = (const int*)d_in[1];
    const float* W1 = (const float*)d_in[2];
    const float* b1 = (const float*)d_in[3];
    const float* W2 = (const float*)d_in[4];
    const float* b2 = (const float*)d_in[5];
    float* out = (float*)d_out;

    const int* src = ei;
    const int* dst = ei + E;

    constexpr size_t NP = NPI;
    int*      cnt   = (int*)d_ws;                         // NP
    int*      rank  = cnt + NP;                           // E
    int*      off   = rank + E;                           // NP (N+1 used)
    float*    dis   = (float*)(off + NP);                 // NP
    int*      bsum  = (int*)(dis + NP);                   // 128
    int*      boff  = bsum + 128;                         // 128
    unsigned* pedge = (unsigned*)(boff + 896);            // E (1024-aligned)
    __hip_bfloat16* h1b = (__hip_bfloat16*)(pedge + E);             // N*64
    __hip_bfloat16* z1b = h1b + (size_t)N * 64;                     // N*64
    __hip_bfloat16* h2b = z1b + (size_t)N * 64;                     // N*32

    hipMemsetAsync(cnt, 0, NP * sizeof(int), stream);
    rank_kernel<<<(E + 255) / 256, 256, 0, stream>>>(dst, cnt, rank);
    blocksum_kernel<<<SCAN_BLOCKS, 256, 0, stream>>>(cnt, bsum);
    scan_bsum_kernel<<<1, 128, 0, stream>>>(bsum, boff);
    scan_write_kernel<<<SCAN_BLOCKS, 256, 0, stream>>>(cnt, boff, off, dis);
    place_kernel<<<(E + 255) / 256, 256, 0, stream>>>(src, dst, rank, dis, off, pedge);

    gemm_kernel<64, false><<<N / 32, 256, 0, stream>>>(x, W1, h1b);
    agg1_kernel<<<(N * 64 + 255) / 256, 256, 0, stream>>>(h1b, pedge, off, dis, b1, z1b);

    gemm_kernel<32, true><<<N / 32, 256, 0, stream>>>(z1b, W2, h2b);
    agg2_kernel<<<(N * 64 + 255) / 256, 256, 0, stream>>>(h2b, pedge, off, dis, b2, out);
}